// Round 1
// baseline (192.059 us; speedup 1.0000x reference)
//
#include <hip/hip_runtime.h>
#include <math.h>

#define NROWS 8192
#define NCOLS 32000
#define NV4   (NCOLS / 4)   // 8000 float4 per row
#define BLK   256

// One block per row: online logsumexp over the row, then focal loss for that row.
__global__ __launch_bounds__(BLK) void focal_row_kernel(
    const float* __restrict__ in,
    const int*   __restrict__ tgt,
    float*       __restrict__ row_loss)
{
    const int row = blockIdx.x;
    const int tid = threadIdx.x;
    const float* rp = in + (size_t)row * NCOLS;
    const float4* rp4 = (const float4*)rp;

    // Per-thread online (max, sum-exp) over strided float4 chunks.
    float m = -INFINITY;
    float s = 0.0f;
    for (int i = tid; i < NV4; i += BLK) {
        float4 v = rp4[i];
        float vm = fmaxf(fmaxf(v.x, v.y), fmaxf(v.z, v.w));
        float nm = fmaxf(m, vm);
        s = s * __expf(m - nm)
          + __expf(v.x - nm) + __expf(v.y - nm)
          + __expf(v.z - nm) + __expf(v.w - nm);
        m = nm;
    }

    // Wave (64-lane) butterfly reduce of (m, s).
    #pragma unroll
    for (int off = 1; off < 64; off <<= 1) {
        float om = __shfl_xor(m, off, 64);
        float os = __shfl_xor(s, off, 64);
        float nm = fmaxf(m, om);
        s = s * __expf(m - nm) + os * __expf(om - nm);
        m = nm;
    }

    // Cross-wave (4 waves) reduce via LDS.
    __shared__ float sm[4];
    __shared__ float ss[4];
    const int wave = tid >> 6;
    const int lane = tid & 63;
    if (lane == 0) { sm[wave] = m; ss[wave] = s; }
    __syncthreads();

    if (tid == 0) {
        float M = sm[0], S = ss[0];
        #pragma unroll
        for (int w = 1; w < 4; ++w) {
            float nm = fmaxf(M, sm[w]);
            S = S * __expf(M - nm) + ss[w] * __expf(sm[w] - nm);
            M = nm;
        }
        float lse   = M + logf(S);          // log-sum-exp of the row
        float xt    = rp[tgt[row]];         // logit at target (L2-warm)
        float logpt = xt - lse;             // log_softmax at target
        float pt    = __expf(logpt);
        float u     = 1.0f - pt;
        row_loss[row] = -(u * u * u) * logpt;   // gamma = 3
    }
}

// Deterministic single-block sum of the 8192 row losses.
__global__ __launch_bounds__(BLK) void sum_kernel(
    const float* __restrict__ row_loss,
    float*       __restrict__ out)
{
    const int tid = threadIdx.x;
    float acc = 0.0f;
    for (int i = tid; i < NROWS; i += BLK) acc += row_loss[i];

    #pragma unroll
    for (int off = 1; off < 64; off <<= 1) acc += __shfl_xor(acc, off, 64);

    __shared__ float ws[4];
    const int wave = tid >> 6;
    const int lane = tid & 63;
    if (lane == 0) ws[wave] = acc;
    __syncthreads();
    if (tid == 0) out[0] = ws[0] + ws[1] + ws[2] + ws[3];
}

extern "C" void kernel_launch(void* const* d_in, const int* in_sizes, int n_in,
                              void* d_out, int out_size, void* d_ws, size_t ws_size,
                              hipStream_t stream) {
    const float* in  = (const float*)d_in[0];
    const int*   tgt = (const int*)d_in[1];
    float* out = (float*)d_out;
    float* ws  = (float*)d_ws;   // 8192 floats = 32 KiB of scratch

    focal_row_kernel<<<NROWS, BLK, 0, stream>>>(in, tgt, ws);
    sum_kernel<<<1, BLK, 0, stream>>>(ws, out);
}

// Round 3
// 172.873 us; speedup vs baseline: 1.1110x; 1.1110x over previous
//
#include <hip/hip_runtime.h>
#include <math.h>

#define NROWS 8192
#define NCOLS 32000
#define NV4   8000          // float4 per row
#define BLK   256
#define ROWS_PER_BLK 4      // one wave (64 lanes) per row

typedef float f32x4 __attribute__((ext_vector_type(4)));  // clang-native vec, ok for nontemporal builtin

// Online accumulate one float4 into (m, s) with deferred rescale:
// only rescale when the running max actually grows (rare on random data).
__device__ __forceinline__ void acc4(const f32x4 v, float& m, float& s) {
    float vm = fmaxf(fmaxf(v.x, v.y), fmaxf(v.z, v.w));
    if (vm > m) { s *= __expf(m - vm); m = vm; }   // exp(-inf)=0 handles first iter
    s += __expf(v.x - m) + __expf(v.y - m) + __expf(v.z - m) + __expf(v.w - m);
}

__global__ __launch_bounds__(BLK) void focal_wave_kernel(
    const float* __restrict__ in,
    const int*   __restrict__ tgt,
    float*       __restrict__ out)
{
    const int wave = threadIdx.x >> 6;
    const int lane = threadIdx.x & 63;
    const int row  = blockIdx.x * ROWS_PER_BLK + wave;
    const float*  rp  = in + (size_t)row * NCOLS;
    const f32x4*  rp4 = (const f32x4*)rp;

    // Early gather of the target logit: its HBM latency hides under the
    // 125-iteration stream below. Wave-uniform address -> one broadcast load.
    const float xt = rp[tgt[row]];

    // 125 float4 per lane = 62 pairs + 1, two independent accumulators for ILP.
    float m0 = -INFINITY, s0 = 0.0f;
    float m1 = -INFINITY, s1 = 0.0f;
    int i = lane;
    for (int k = 0; k < 62; ++k, i += 128) {
        f32x4 a = __builtin_nontemporal_load(&rp4[i]);
        f32x4 b = __builtin_nontemporal_load(&rp4[i + 64]);
        acc4(a, m0, s0);
        acc4(b, m1, s1);
    }
    {   // remainder (iteration 125)
        f32x4 a = __builtin_nontemporal_load(&rp4[i]);
        acc4(a, m0, s0);
    }

    // Merge the two accumulators.
    float m = fmaxf(m0, m1);
    float s = s0 * __expf(m0 - m) + s1 * __expf(m1 - m);

    // In-wave butterfly reduce of (m, s) — no LDS, no barrier.
    #pragma unroll
    for (int off = 1; off < 64; off <<= 1) {
        float om = __shfl_xor(m, off, 64);
        float os = __shfl_xor(s, off, 64);
        float nm = fmaxf(m, om);
        s = s * __expf(m - nm) + os * __expf(om - nm);
        m = nm;
    }

    // Per-wave row loss -> LDS; one atomicAdd per block (2048 total).
    __shared__ float part[ROWS_PER_BLK];
    if (lane == 0) {
        float lse   = m + logf(s);
        float logpt = xt - lse;
        float pt    = __expf(logpt);
        float u     = 1.0f - pt;
        part[wave]  = -(u * u * u) * logpt;   // gamma = 3
    }
    __syncthreads();
    if (threadIdx.x == 0) {
        atomicAdd(out, part[0] + part[1] + part[2] + part[3]);
    }
}

extern "C" void kernel_launch(void* const* d_in, const int* in_sizes, int n_in,
                              void* d_out, int out_size, void* d_ws, size_t ws_size,
                              hipStream_t stream) {
    const float* in  = (const float*)d_in[0];
    const int*   tgt = (const int*)d_in[1];
    float* out = (float*)d_out;

    // d_out accumulates via atomics; harness does not re-zero between replays.
    (void)hipMemsetAsync(out, 0, sizeof(float), stream);
    focal_wave_kernel<<<NROWS / ROWS_PER_BLK, BLK, 0, stream>>>(in, tgt, out);
}